// Round 1
// baseline (263.250 us; speedup 1.0000x reference)
//
#include <hip/hip_runtime.h>

#define Bn 256
#define Nn 64
#define Tn 50
#define Fn 2
#define En 64
#define Hn 128
#define Rn 30
#define G4 512   // 4*H

__device__ __forceinline__ float sigf(float x) { return 1.0f / (1.0f + expf(-x)); }

// ---------------- Phase 1: emb[b,t,e] = relu(gcn + x@W_res)[node 0] ----------------
// One wave per (b,t) task. Lane j owns node j.
__global__ __launch_bounds__(256) void k_emb(const float* __restrict__ src,
                                             const float* __restrict__ W_res,
                                             const float* __restrict__ W_gcn,
                                             const float* __restrict__ b_gcn,
                                             float* __restrict__ emb)
{
    const int wave = threadIdx.x >> 6;
    const int lane = threadIdx.x & 63;
    const int task = blockIdx.x * 4 + wave;      // task = b*Tn + t, grid covers exactly Bn*Tn
    const int b = task / Tn;
    const int t = task - b * Tn;

    __shared__ float xs0[4][Nn];
    __shared__ float xs1[4][Nn];

    // x[b,t,n,f] = src[b,n,t,f]; lane loads node `lane`
    const float2 xv = *reinterpret_cast<const float2*>(
        src + (((size_t)b * Nn + lane) * Tn + t) * Fn);
    const float x0 = xv.x, x1 = xv.y;
    xs0[wave][lane] = x0;
    xs1[wave][lane] = x1;
    __syncthreads();

    // lane j: rowsum_j = sum_k w[j,k] (diag=1), w0 = w[0,j] (symmetric = w[j,0])
    float rowsum = 0.0f, w0 = 0.0f;
    for (int k = 0; k < Nn; k++) {
        const float dx = x0 - xs0[wave][k];
        const float dy = x1 - xs1[wave][k];
        const float d  = sqrtf(dx * dx + dy * dy);
        float w = fminf(1.0f / fmaxf(d, 1e-6f), 1.0f);
        if (k == lane) w = 1.0f;          // eye: diagonal forced to 1
        rowsum += w;
        if (k == 0) w0 = w;
    }
    const float dinv  = 1.0f / sqrtf(rowsum);
    const float dinv0 = __shfl(dinv, 0);
    const float a = w0 * dinv0 * dinv;    // A[0, j]

    // s_f = sum_j A0j * x[j,f]  (butterfly all-reduce)
    float p0 = a * x0, p1 = a * x1;
    #pragma unroll
    for (int off = 32; off; off >>= 1) {
        p0 += __shfl_xor(p0, off);
        p1 += __shfl_xor(p1, off);
    }
    const float xa = __shfl(x0, 0);       // x[b,t,0,:]
    const float xb = __shfl(x1, 0);

    const float v = p0 * W_gcn[lane] + p1 * W_gcn[En + lane] + b_gcn[lane]
                  + xa * W_res[lane] + xb * W_res[En + lane];
    emb[(size_t)task * En + lane] = fmaxf(v, 0.0f);
}

// ---------------- Phase 2+3: encoder LSTM (T steps) + decoder LSTM (R steps) ----------------
// One block per batch element. Thread j owns gate column j; weights live in VGPRs.
__global__ __launch_bounds__(512, 2) void k_seq(
    const float* __restrict__ emb,
    const float* __restrict__ src,
    const float* __restrict__ W_ih_e, const float* __restrict__ W_hh_e, const float* __restrict__ b_e,
    const float* __restrict__ W1,     const float* __restrict__ b1,
    const float* __restrict__ W_ih_d, const float* __restrict__ W_hh_d, const float* __restrict__ b_d,
    const float* __restrict__ W2,     const float* __restrict__ b2,
    float* __restrict__ out)
{
    const int j = threadIdx.x;   // 0..511 gate column
    const int b = blockIdx.x;    // batch element

    __shared__ __align__(16) float h_lds[Hn];
    __shared__ __align__(16) float g_lds[G4];
    __shared__ __align__(16) float xt_lds[En];
    __shared__ float xin_lds[2];
    __shared__ float red[4];

    float wih[En], whh[Hn];
    float bias;

    // ---- encoder weights into registers (column j) ----
    #pragma unroll
    for (int k = 0; k < En; k++) wih[k] = W_ih_e[k * G4 + j];
    #pragma unroll
    for (int k = 0; k < Hn; k++) whh[k] = W_hh_e[k * G4 + j];
    bias = b_e[j];

    float c = 0.0f;
    if (j < Hn) h_lds[j] = 0.0f;
    __syncthreads();

    // ---- encoder: 50 steps ----
    for (int t = 0; t < Tn; t++) {
        const float4* x4 = reinterpret_cast<const float4*>(emb + ((size_t)b * Tn + t) * En);
        const float4* h4 = reinterpret_cast<const float4*>(h_lds);
        float a0 = bias, a1 = 0.0f;
        #pragma unroll
        for (int k = 0; k < En / 4; k++) {
            const float4 u = x4[k];
            a0 += u.x * wih[4 * k + 0] + u.z * wih[4 * k + 2];
            a1 += u.y * wih[4 * k + 1] + u.w * wih[4 * k + 3];
        }
        #pragma unroll
        for (int k = 0; k < Hn / 4; k++) {
            const float4 u = h4[k];
            a0 += u.x * whh[4 * k + 0] + u.z * whh[4 * k + 2];
            a1 += u.y * whh[4 * k + 1] + u.w * whh[4 * k + 3];
        }
        g_lds[j] = a0 + a1;
        __syncthreads();
        if (j < Hn) {
            const float gi = g_lds[j];
            const float gf = g_lds[Hn + j];
            const float gg = g_lds[2 * Hn + j];
            const float go = g_lds[3 * Hn + j];
            c = sigf(gf) * c + sigf(gi) * tanhf(gg);
            h_lds[j] = sigf(go) * tanhf(c);
        }
        __syncthreads();
    }

    // ---- decoder weights into registers ----
    #pragma unroll
    for (int k = 0; k < En; k++) wih[k] = W_ih_d[k * G4 + j];
    #pragma unroll
    for (int k = 0; k < Hn; k++) whh[k] = W_hh_d[k * G4 + j];
    bias = b_d[j];

    float w1a = 0.0f, w1b = 0.0f, b1v = 0.0f, w2a = 0.0f, w2b = 0.0f;
    if (j < En) { w1a = W1[j]; w1b = W1[En + j]; b1v = b1[j]; }
    if (j < Hn) { w2a = W2[2 * j]; w2b = W2[2 * j + 1]; }

    // xin = x[b, T-1, node 0, :] = src[b, 0, T-1, :]
    float xin0 = src[(size_t)b * Nn * Tn * Fn + (Tn - 1) * Fn + 0];
    float xin1 = src[(size_t)b * Nn * Tn * Fn + (Tn - 1) * Fn + 1];

    // ---- decoder: 30 steps ----
    for (int r = 0; r < Rn; r++) {
        if (j < En) xt_lds[j] = fmaxf(xin0 * w1a + xin1 * w1b + b1v, 0.0f);
        __syncthreads();

        const float4* x4 = reinterpret_cast<const float4*>(xt_lds);
        const float4* h4 = reinterpret_cast<const float4*>(h_lds);
        float a0 = bias, a1 = 0.0f;
        #pragma unroll
        for (int k = 0; k < En / 4; k++) {
            const float4 u = x4[k];
            a0 += u.x * wih[4 * k + 0] + u.z * wih[4 * k + 2];
            a1 += u.y * wih[4 * k + 1] + u.w * wih[4 * k + 3];
        }
        #pragma unroll
        for (int k = 0; k < Hn / 4; k++) {
            const float4 u = h4[k];
            a0 += u.x * whh[4 * k + 0] + u.z * whh[4 * k + 2];
            a1 += u.y * whh[4 * k + 1] + u.w * whh[4 * k + 3];
        }
        g_lds[j] = a0 + a1;
        __syncthreads();

        if (j < Hn) {
            const float gi = g_lds[j];
            const float gf = g_lds[Hn + j];
            const float gg = g_lds[2 * Hn + j];
            const float go = g_lds[3 * Hn + j];
            c = sigf(gf) * c + sigf(gi) * tanhf(gg);
            const float hn = sigf(go) * tanhf(c);
            h_lds[j] = hn;
            // out = h @ W2 + b2 : per-wave butterfly partial sums
            float p0 = hn * w2a, p1 = hn * w2b;
            #pragma unroll
            for (int off = 32; off; off >>= 1) {
                p0 += __shfl_xor(p0, off);
                p1 += __shfl_xor(p1, off);
            }
            if ((j & 63) == 0) {
                red[(j >> 6) * 2 + 0] = p0;
                red[(j >> 6) * 2 + 1] = p1;
            }
        }
        __syncthreads();

        if (j < 2) {
            const float o = red[j] + red[2 + j] + b2[j];
            out[((size_t)b * Rn + r) * Fn + j] = o;
            xin_lds[j] = o;
        }
        __syncthreads();
        xin0 = xin_lds[0];
        xin1 = xin_lds[1];
    }
}

extern "C" void kernel_launch(void* const* d_in, const int* in_sizes, int n_in,
                              void* d_out, int out_size, void* d_ws, size_t ws_size,
                              hipStream_t stream)
{
    const float* src    = (const float*)d_in[0];
    // d_in[1] = trg (unused by the forward pass)
    const float* W_res  = (const float*)d_in[2];
    const float* W_gcn  = (const float*)d_in[3];
    const float* b_gcn  = (const float*)d_in[4];
    const float* W_ih_e = (const float*)d_in[5];
    const float* W_hh_e = (const float*)d_in[6];
    const float* b_e    = (const float*)d_in[7];
    const float* W1     = (const float*)d_in[8];
    const float* b1     = (const float*)d_in[9];
    const float* W_ih_d = (const float*)d_in[10];
    const float* W_hh_d = (const float*)d_in[11];
    const float* b_d    = (const float*)d_in[12];
    const float* W2     = (const float*)d_in[13];
    const float* b2     = (const float*)d_in[14];

    float* out = (float*)d_out;
    float* emb = (float*)d_ws;   // Bn*Tn*En floats = 3.28 MB scratch

    k_emb<<<(Bn * Tn) / 4, 256, 0, stream>>>(src, W_res, W_gcn, b_gcn, emb);
    k_seq<<<Bn, 512, 0, stream>>>(emb, src,
                                  W_ih_e, W_hh_e, b_e,
                                  W1, b1,
                                  W_ih_d, W_hh_d, b_d,
                                  W2, b2, out);
}

// Round 2
// 214.625 us; speedup vs baseline: 1.2266x; 1.2266x over previous
//
#include <hip/hip_runtime.h>

#define Bn 256
#define Nn 64
#define Tn 50
#define Fn 2
#define En 64
#define Hn 128
#define Rn 30
#define G4 512   // 4*H
#define Kd 192   // xt(64) + h(128)

__device__ __forceinline__ float sigf(float x) {
    return __builtin_amdgcn_rcpf(1.0f + __expf(-x));
}
__device__ __forceinline__ float tanh_fast(float x) {
    // tanh(x) = 1 - 2/(exp(2x)+1); stable both tails in fp32
    return 1.0f - 2.0f * __builtin_amdgcn_rcpf(__expf(2.0f * x) + 1.0f);
}

// ---------------- Phase 1: emb[b*T+t, e] = relu(gcn + x@W_res) at node 0 ----------------
// One wave per (b,t); lane j owns node j.
__global__ __launch_bounds__(256) void k_emb(const float* __restrict__ src,
                                             const float* __restrict__ W_res,
                                             const float* __restrict__ W_gcn,
                                             const float* __restrict__ b_gcn,
                                             float* __restrict__ emb)
{
    const int wave = threadIdx.x >> 6;
    const int lane = threadIdx.x & 63;
    const int task = blockIdx.x * 4 + wave;      // b*Tn + t
    const int b = task / Tn;
    const int t = task - b * Tn;

    __shared__ float2 xs[4][Nn];

    const float2 xv = *reinterpret_cast<const float2*>(
        src + (((size_t)b * Nn + lane) * Tn + t) * Fn);
    const float x0 = xv.x, x1 = xv.y;
    xs[wave][lane] = xv;
    __syncthreads();

    // w[j,k] = min(1/dist,1) with dist==0 -> 1 ; v_rsq(0)=+inf reproduces both
    // the 1e-6 clamp and the eye-diagonal exactly (min(inf,1)=1).
    float rowsum = 0.0f, w0 = 0.0f;
    #pragma unroll
    for (int k = 0; k < Nn; k++) {
        const float2 o = xs[wave][k];
        const float dx = x0 - o.x, dy = x1 - o.y;
        const float w = fminf(__builtin_amdgcn_rsqf(dx * dx + dy * dy), 1.0f);
        rowsum += w;
        if (k == 0) w0 = w;
    }
    const float dinv  = __builtin_amdgcn_rsqf(rowsum);   // rowsum >= 1
    const float dinv0 = __shfl(dinv, 0);
    const float a = w0 * dinv0 * dinv;    // A[0, j]

    float p0 = a * x0, p1 = a * x1;
    #pragma unroll
    for (int off = 32; off; off >>= 1) {
        p0 += __shfl_xor(p0, off);
        p1 += __shfl_xor(p1, off);
    }
    const float xa = __shfl(x0, 0);
    const float xb = __shfl(x1, 0);

    const float v = p0 * W_gcn[lane] + p1 * W_gcn[En + lane] + b_gcn[lane]
                  + xa * W_res[lane] + xb * W_res[En + lane];
    emb[(size_t)task * En + lane] = fmaxf(v, 0.0f);
}

// ---------------- Phase 2+3: encoder (T) + decoder (R) LSTM ----------------
// 512 threads / block, 1 batch element / block.
// Thread (j2 = (lane&15)+16*wave, s = lane>>4): partial gates for cell j2
// over k-chunk [48s,48s+48) of v = [xt(64)|h(128)]; butterfly over s in-wave.
__global__ __launch_bounds__(512, 2) void k_seq(
    const float* __restrict__ emb,
    const float* __restrict__ src,
    const float* __restrict__ W_ih_e, const float* __restrict__ W_hh_e, const float* __restrict__ b_e,
    const float* __restrict__ W1,     const float* __restrict__ b1,
    const float* __restrict__ W_ih_d, const float* __restrict__ W_hh_d, const float* __restrict__ b_d,
    const float* __restrict__ W2,     const float* __restrict__ b2,
    float* __restrict__ out)
{
    const int tid  = threadIdx.x;
    const int lane = tid & 63;
    const int wv   = tid >> 6;            // 0..7
    const int s    = lane >> 4;           // 0..3 k-chunk (wave-quarter)
    const int j2   = (lane & 15) + (wv << 4);  // 0..127 cell index
    const int b    = blockIdx.x;

    __shared__ __align__(16) float vbuf[2][Kd];
    __shared__ float red[8][2];
    __shared__ float xin_sh[2];

    float w[Kd];     // w[m*48+kk] = Wcat[48s+kk][j2+128m], register-pinned
    float bias[4];
    float c = 0.0f;

    // ---- encoder weights into VGPRs (pinned: prevents per-step re-streaming) ----
    #pragma unroll
    for (int m = 0; m < 4; m++) {
        const int col = j2 + (m << 7);
        #pragma unroll
        for (int kk = 0; kk < 48; kk++) {
            const int k = s * 48 + kk;
            const float* p = (k < En) ? (W_ih_e + (size_t)k * G4 + col)
                                      : (W_hh_e + (size_t)(k - En) * G4 + col);
            float v = *p;
            asm volatile("" : "+v"(v));
            w[m * 48 + kk] = v;
        }
        float bv = b_e[col];
        asm volatile("" : "+v"(bv));
        bias[m] = bv;
    }

    const float* emb_b = emb + (size_t)b * Tn * En;

    // init: vbuf[0] = [emb row 0 | h=0]
    if (tid < En) vbuf[0][tid] = emb_b[tid];
    if (tid < Hn) vbuf[0][En + tid] = 0.0f;
    __syncthreads();

    // ---- encoder: 50 steps, 1 barrier/step ----
    #pragma unroll 2
    for (int t = 0; t < Tn; t++) {
        const int cur = t & 1;
        float xt_next = 0.0f;
        if (tid < En && t + 1 < Tn) xt_next = emb_b[(t + 1) * En + tid];

        const float4* v4 = reinterpret_cast<const float4*>(&vbuf[cur][s * 48]);
        float a0 = 0.0f, a1 = 0.0f, a2 = 0.0f, a3 = 0.0f;
        #pragma unroll
        for (int i = 0; i < 12; i++) {
            const float4 u = v4[i];
            a0 = fmaf(u.x, w[0*48+4*i+0], a0); a0 = fmaf(u.y, w[0*48+4*i+1], a0);
            a0 = fmaf(u.z, w[0*48+4*i+2], a0); a0 = fmaf(u.w, w[0*48+4*i+3], a0);
            a1 = fmaf(u.x, w[1*48+4*i+0], a1); a1 = fmaf(u.y, w[1*48+4*i+1], a1);
            a1 = fmaf(u.z, w[1*48+4*i+2], a1); a1 = fmaf(u.w, w[1*48+4*i+3], a1);
            a2 = fmaf(u.x, w[2*48+4*i+0], a2); a2 = fmaf(u.y, w[2*48+4*i+1], a2);
            a2 = fmaf(u.z, w[2*48+4*i+2], a2); a2 = fmaf(u.w, w[2*48+4*i+3], a2);
            a3 = fmaf(u.x, w[3*48+4*i+0], a3); a3 = fmaf(u.y, w[3*48+4*i+1], a3);
            a3 = fmaf(u.z, w[3*48+4*i+2], a3); a3 = fmaf(u.w, w[3*48+4*i+3], a3);
        }
        // butterfly all-reduce over the 4 s-lanes sharing this j2
        a0 += __shfl_xor(a0, 16); a1 += __shfl_xor(a1, 16);
        a2 += __shfl_xor(a2, 16); a3 += __shfl_xor(a3, 16);
        a0 += __shfl_xor(a0, 32); a1 += __shfl_xor(a1, 32);
        a2 += __shfl_xor(a2, 32); a3 += __shfl_xor(a3, 32);

        const float gi = a0 + bias[0], gf = a1 + bias[1];
        const float gg = a2 + bias[2], go = a3 + bias[3];
        c = sigf(gf) * c + sigf(gi) * tanh_fast(gg);
        const float h = sigf(go) * tanh_fast(c);

        if (s == 0) vbuf[cur ^ 1][En + j2] = h;
        if (tid < En && t + 1 < Tn) vbuf[cur ^ 1][tid] = xt_next;
        __syncthreads();
    }

    // ---- decoder weights into VGPRs ----
    #pragma unroll
    for (int m = 0; m < 4; m++) {
        const int col = j2 + (m << 7);
        #pragma unroll
        for (int kk = 0; kk < 48; kk++) {
            const int k = s * 48 + kk;
            const float* p = (k < En) ? (W_ih_d + (size_t)k * G4 + col)
                                      : (W_hh_d + (size_t)(k - En) * G4 + col);
            float v = *p;
            asm volatile("" : "+v"(v));
            w[m * 48 + kk] = v;
        }
        float bv = b_d[col];
        asm volatile("" : "+v"(bv));
        bias[m] = bv;
    }
    float w1a = 0.0f, w1b = 0.0f, b1v = 0.0f;
    if (tid < En) { w1a = W1[tid]; w1b = W1[En + tid]; b1v = b1[tid]; }
    const float w2a = W2[2 * j2], w2b = W2[2 * j2 + 1];

    const float xin0 = src[(size_t)b * Nn * Tn * Fn + (Tn - 1) * Fn + 0];
    const float xin1 = src[(size_t)b * Nn * Tn * Fn + (Tn - 1) * Fn + 1];
    if (tid < En) vbuf[0][tid] = fmaxf(xin0 * w1a + xin1 * w1b + b1v, 0.0f);
    __syncthreads();

    // ---- decoder: 30 steps, 3 barriers/step ----
    #pragma unroll 2
    for (int r = 0; r < Rn; r++) {
        const int cur = r & 1;
        const float4* v4 = reinterpret_cast<const float4*>(&vbuf[cur][s * 48]);
        float a0 = 0.0f, a1 = 0.0f, a2 = 0.0f, a3 = 0.0f;
        #pragma unroll
        for (int i = 0; i < 12; i++) {
            const float4 u = v4[i];
            a0 = fmaf(u.x, w[0*48+4*i+0], a0); a0 = fmaf(u.y, w[0*48+4*i+1], a0);
            a0 = fmaf(u.z, w[0*48+4*i+2], a0); a0 = fmaf(u.w, w[0*48+4*i+3], a0);
            a1 = fmaf(u.x, w[1*48+4*i+0], a1); a1 = fmaf(u.y, w[1*48+4*i+1], a1);
            a1 = fmaf(u.z, w[1*48+4*i+2], a1); a1 = fmaf(u.w, w[1*48+4*i+3], a1);
            a2 = fmaf(u.x, w[2*48+4*i+0], a2); a2 = fmaf(u.y, w[2*48+4*i+1], a2);
            a2 = fmaf(u.z, w[2*48+4*i+2], a2); a2 = fmaf(u.w, w[2*48+4*i+3], a2);
            a3 = fmaf(u.x, w[3*48+4*i+0], a3); a3 = fmaf(u.y, w[3*48+4*i+1], a3);
            a3 = fmaf(u.z, w[3*48+4*i+2], a3); a3 = fmaf(u.w, w[3*48+4*i+3], a3);
        }
        a0 += __shfl_xor(a0, 16); a1 += __shfl_xor(a1, 16);
        a2 += __shfl_xor(a2, 16); a3 += __shfl_xor(a3, 16);
        a0 += __shfl_xor(a0, 32); a1 += __shfl_xor(a1, 32);
        a2 += __shfl_xor(a2, 32); a3 += __shfl_xor(a3, 32);

        const float gi = a0 + bias[0], gf = a1 + bias[1];
        const float gg = a2 + bias[2], go = a3 + bias[3];
        c = sigf(gf) * c + sigf(gi) * tanh_fast(gg);
        const float h = sigf(go) * tanh_fast(c);

        if (s == 0) vbuf[cur ^ 1][En + j2] = h;

        // out = h @ W2 + b2 (s==0 copies only contribute)
        float p0 = (s == 0) ? h * w2a : 0.0f;
        float p1 = (s == 0) ? h * w2b : 0.0f;
        #pragma unroll
        for (int off = 32; off; off >>= 1) {
            p0 += __shfl_xor(p0, off);
            p1 += __shfl_xor(p1, off);
        }
        if (lane == 0) { red[wv][0] = p0; red[wv][1] = p1; }
        __syncthreads();

        if (tid < 2) {
            float o = b2[tid];
            #pragma unroll
            for (int k2 = 0; k2 < 8; k2++) o += red[k2][tid];
            out[((size_t)b * Rn + r) * Fn + tid] = o;
            xin_sh[tid] = o;
        }
        __syncthreads();

        if (r + 1 < Rn && tid < En) {
            vbuf[cur ^ 1][tid] = fmaxf(xin_sh[0] * w1a + xin_sh[1] * w1b + b1v, 0.0f);
        }
        __syncthreads();
    }
}

extern "C" void kernel_launch(void* const* d_in, const int* in_sizes, int n_in,
                              void* d_out, int out_size, void* d_ws, size_t ws_size,
                              hipStream_t stream)
{
    const float* src    = (const float*)d_in[0];
    const float* W_res  = (const float*)d_in[2];
    const float* W_gcn  = (const float*)d_in[3];
    const float* b_gcn  = (const float*)d_in[4];
    const float* W_ih_e = (const float*)d_in[5];
    const float* W_hh_e = (const float*)d_in[6];
    const float* b_e    = (const float*)d_in[7];
    const float* W1     = (const float*)d_in[8];
    const float* b1     = (const float*)d_in[9];
    const float* W_ih_d = (const float*)d_in[10];
    const float* W_hh_d = (const float*)d_in[11];
    const float* b_d    = (const float*)d_in[12];
    const float* W2     = (const float*)d_in[13];
    const float* b2     = (const float*)d_in[14];

    float* out = (float*)d_out;
    float* emb = (float*)d_ws;   // Bn*Tn*En floats = 3.28 MB scratch

    k_emb<<<(Bn * Tn) / 4, 256, 0, stream>>>(src, W_res, W_gcn, b_gcn, emb);
    k_seq<<<Bn, 512, 0, stream>>>(emb, src,
                                  W_ih_e, W_hh_e, b_e,
                                  W1, b1,
                                  W_ih_d, W_hh_d, b_d,
                                  W2, b2, out);
}

// Round 3
// 214.448 us; speedup vs baseline: 1.2276x; 1.0008x over previous
//
#include <hip/hip_runtime.h>

#define Bn 256
#define Nn 64
#define Tn 50
#define Fn 2
#define En 64
#define Hn 128
#define Rn 30
#define G4 512   // 4*H
#define Kd 192   // xt(64) + h(128)

__device__ __forceinline__ float sigf(float x) {
    return __builtin_amdgcn_rcpf(1.0f + __expf(-x));
}
__device__ __forceinline__ float tanh_fast(float x) {
    // tanh(x) = 1 - 2/(exp(2x)+1); stable both tails in fp32
    return 1.0f - 2.0f * __builtin_amdgcn_rcpf(__expf(2.0f * x) + 1.0f);
}

// ---------------- Phase 1: emb[b*T+t, e] = relu(gcn + x@W_res) at node 0 ----------------
// One wave per (b,t); lane j owns node j.
__global__ __launch_bounds__(256) void k_emb(const float* __restrict__ src,
                                             const float* __restrict__ W_res,
                                             const float* __restrict__ W_gcn,
                                             const float* __restrict__ b_gcn,
                                             float* __restrict__ emb)
{
    const int wave = threadIdx.x >> 6;
    const int lane = threadIdx.x & 63;
    const int task = blockIdx.x * 4 + wave;      // b*Tn + t
    const int b = task / Tn;
    const int t = task - b * Tn;

    __shared__ float2 xs[4][Nn];

    const float2 xv = *reinterpret_cast<const float2*>(
        src + (((size_t)b * Nn + lane) * Tn + t) * Fn);
    const float x0 = xv.x, x1 = xv.y;
    xs[wave][lane] = xv;
    __syncthreads();

    // w[j,k] = min(1/dist,1); v_rsq(0)=+inf reproduces the 1e-6 clamp and
    // the eye-diagonal exactly (min(inf,1)=1).
    float rowsum = 0.0f, w0 = 0.0f;
    #pragma unroll
    for (int k = 0; k < Nn; k++) {
        const float2 o = xs[wave][k];
        const float dx = x0 - o.x, dy = x1 - o.y;
        const float w = fminf(__builtin_amdgcn_rsqf(dx * dx + dy * dy), 1.0f);
        rowsum += w;
        if (k == 0) w0 = w;
    }
    const float dinv  = __builtin_amdgcn_rsqf(rowsum);   // rowsum >= 1
    const float dinv0 = __shfl(dinv, 0);
    const float a = w0 * dinv0 * dinv;    // A[0, j]

    float p0 = a * x0, p1 = a * x1;
    #pragma unroll
    for (int off = 32; off; off >>= 1) {
        p0 += __shfl_xor(p0, off);
        p1 += __shfl_xor(p1, off);
    }
    const float xa = __shfl(x0, 0);
    const float xb = __shfl(x1, 0);

    const float v = p0 * W_gcn[lane] + p1 * W_gcn[En + lane] + b_gcn[lane]
                  + xa * W_res[lane] + xb * W_res[En + lane];
    emb[(size_t)task * En + lane] = fmaxf(v, 0.0f);
}

// ---------------- Phase 2+3: encoder (T) + decoder (R) LSTM ----------------
// 512 threads / block, 1 batch element / block.
// Thread (j2 = (lane&15)+16*wave, s = lane>>4): partial gates for cell j2
// over k-chunk [48s,48s+48) of v = [xt(64)|h(128)]; butterfly over s in-wave.
// amdgpu_waves_per_eu(2,2): pins the register budget to 256 VGPRs (512/2) so
// the 192-float weight array stays register-resident. R2 showed that
// __launch_bounds__(512,2) alone (min-only) lets the backend target 4
// waves/EU -> 128-VGPR budget -> 100 MB scratch spill.
__global__ __launch_bounds__(512)
__attribute__((amdgpu_waves_per_eu(2, 2)))
void k_seq(
    const float* __restrict__ emb,
    const float* __restrict__ src,
    const float* __restrict__ W_ih_e, const float* __restrict__ W_hh_e, const float* __restrict__ b_e,
    const float* __restrict__ W1,     const float* __restrict__ b1,
    const float* __restrict__ W_ih_d, const float* __restrict__ W_hh_d, const float* __restrict__ b_d,
    const float* __restrict__ W2,     const float* __restrict__ b2,
    float* __restrict__ out)
{
    const int tid  = threadIdx.x;
    const int lane = tid & 63;
    const int wv   = tid >> 6;            // 0..7
    const int s    = lane >> 4;           // 0..3 k-chunk (wave-quarter)
    const int j2   = (lane & 15) + (wv << 4);  // 0..127 cell index
    const int b    = blockIdx.x;

    __shared__ __align__(16) float vbuf[2][Kd];
    __shared__ float red[8][2];
    __shared__ float xin_sh[2];

    float w[Kd];     // w[m*48+kk] = Wcat[48s+kk][j2+128m], register-resident
    float bias[4];
    float c = 0.0f;

    // ---- encoder weights into VGPRs ----
    #pragma unroll
    for (int m = 0; m < 4; m++) {
        const int col = j2 + (m << 7);
        #pragma unroll
        for (int kk = 0; kk < 48; kk++) {
            const int k = s * 48 + kk;
            const float* p = (k < En) ? (W_ih_e + (size_t)k * G4 + col)
                                      : (W_hh_e + (size_t)(k - En) * G4 + col);
            float v = *p;
            asm volatile("" : "+v"(v));
            w[m * 48 + kk] = v;
        }
        float bv = b_e[col];
        asm volatile("" : "+v"(bv));
        bias[m] = bv;
    }

    const float* emb_b = emb + (size_t)b * Tn * En;

    // init: vbuf[0] = [emb row 0 | h=0]
    if (tid < En) vbuf[0][tid] = emb_b[tid];
    if (tid < Hn) vbuf[0][En + tid] = 0.0f;
    __syncthreads();

    // ---- encoder: 50 steps, 1 barrier/step ----
    #pragma unroll 2
    for (int t = 0; t < Tn; t++) {
        const int cur = t & 1;
        float xt_next = 0.0f;
        if (tid < En && t + 1 < Tn) xt_next = emb_b[(t + 1) * En + tid];

        const float4* v4 = reinterpret_cast<const float4*>(&vbuf[cur][s * 48]);
        float a0 = 0.0f, a1 = 0.0f, a2 = 0.0f, a3 = 0.0f;
        #pragma unroll
        for (int i = 0; i < 12; i++) {
            const float4 u = v4[i];
            a0 = fmaf(u.x, w[0*48+4*i+0], a0); a0 = fmaf(u.y, w[0*48+4*i+1], a0);
            a0 = fmaf(u.z, w[0*48+4*i+2], a0); a0 = fmaf(u.w, w[0*48+4*i+3], a0);
            a1 = fmaf(u.x, w[1*48+4*i+0], a1); a1 = fmaf(u.y, w[1*48+4*i+1], a1);
            a1 = fmaf(u.z, w[1*48+4*i+2], a1); a1 = fmaf(u.w, w[1*48+4*i+3], a1);
            a2 = fmaf(u.x, w[2*48+4*i+0], a2); a2 = fmaf(u.y, w[2*48+4*i+1], a2);
            a2 = fmaf(u.z, w[2*48+4*i+2], a2); a2 = fmaf(u.w, w[2*48+4*i+3], a2);
            a3 = fmaf(u.x, w[3*48+4*i+0], a3); a3 = fmaf(u.y, w[3*48+4*i+1], a3);
            a3 = fmaf(u.z, w[3*48+4*i+2], a3); a3 = fmaf(u.w, w[3*48+4*i+3], a3);
        }
        // butterfly all-reduce over the 4 s-lanes sharing this j2
        a0 += __shfl_xor(a0, 16); a1 += __shfl_xor(a1, 16);
        a2 += __shfl_xor(a2, 16); a3 += __shfl_xor(a3, 16);
        a0 += __shfl_xor(a0, 32); a1 += __shfl_xor(a1, 32);
        a2 += __shfl_xor(a2, 32); a3 += __shfl_xor(a3, 32);

        const float gi = a0 + bias[0], gf = a1 + bias[1];
        const float gg = a2 + bias[2], go = a3 + bias[3];
        c = sigf(gf) * c + sigf(gi) * tanh_fast(gg);
        const float h = sigf(go) * tanh_fast(c);

        if (s == 0) vbuf[cur ^ 1][En + j2] = h;
        if (tid < En && t + 1 < Tn) vbuf[cur ^ 1][tid] = xt_next;
        __syncthreads();
    }

    // ---- decoder weights into VGPRs ----
    #pragma unroll
    for (int m = 0; m < 4; m++) {
        const int col = j2 + (m << 7);
        #pragma unroll
        for (int kk = 0; kk < 48; kk++) {
            const int k = s * 48 + kk;
            const float* p = (k < En) ? (W_ih_d + (size_t)k * G4 + col)
                                      : (W_hh_d + (size_t)(k - En) * G4 + col);
            float v = *p;
            asm volatile("" : "+v"(v));
            w[m * 48 + kk] = v;
        }
        float bv = b_d[col];
        asm volatile("" : "+v"(bv));
        bias[m] = bv;
    }
    float w1a = 0.0f, w1b = 0.0f, b1v = 0.0f;
    if (tid < En) { w1a = W1[tid]; w1b = W1[En + tid]; b1v = b1[tid]; }
    const float w2a = W2[2 * j2], w2b = W2[2 * j2 + 1];

    const float xin0 = src[(size_t)b * Nn * Tn * Fn + (Tn - 1) * Fn + 0];
    const float xin1 = src[(size_t)b * Nn * Tn * Fn + (Tn - 1) * Fn + 1];
    if (tid < En) vbuf[0][tid] = fmaxf(xin0 * w1a + xin1 * w1b + b1v, 0.0f);
    __syncthreads();

    // ---- decoder: 30 steps, 3 barriers/step ----
    #pragma unroll 2
    for (int r = 0; r < Rn; r++) {
        const int cur = r & 1;
        const float4* v4 = reinterpret_cast<const float4*>(&vbuf[cur][s * 48]);
        float a0 = 0.0f, a1 = 0.0f, a2 = 0.0f, a3 = 0.0f;
        #pragma unroll
        for (int i = 0; i < 12; i++) {
            const float4 u = v4[i];
            a0 = fmaf(u.x, w[0*48+4*i+0], a0); a0 = fmaf(u.y, w[0*48+4*i+1], a0);
            a0 = fmaf(u.z, w[0*48+4*i+2], a0); a0 = fmaf(u.w, w[0*48+4*i+3], a0);
            a1 = fmaf(u.x, w[1*48+4*i+0], a1); a1 = fmaf(u.y, w[1*48+4*i+1], a1);
            a1 = fmaf(u.z, w[1*48+4*i+2], a1); a1 = fmaf(u.w, w[1*48+4*i+3], a1);
            a2 = fmaf(u.x, w[2*48+4*i+0], a2); a2 = fmaf(u.y, w[2*48+4*i+1], a2);
            a2 = fmaf(u.z, w[2*48+4*i+2], a2); a2 = fmaf(u.w, w[2*48+4*i+3], a2);
            a3 = fmaf(u.x, w[3*48+4*i+0], a3); a3 = fmaf(u.y, w[3*48+4*i+1], a3);
            a3 = fmaf(u.z, w[3*48+4*i+2], a3); a3 = fmaf(u.w, w[3*48+4*i+3], a3);
        }
        a0 += __shfl_xor(a0, 16); a1 += __shfl_xor(a1, 16);
        a2 += __shfl_xor(a2, 16); a3 += __shfl_xor(a3, 16);
        a0 += __shfl_xor(a0, 32); a1 += __shfl_xor(a1, 32);
        a2 += __shfl_xor(a2, 32); a3 += __shfl_xor(a3, 32);

        const float gi = a0 + bias[0], gf = a1 + bias[1];
        const float gg = a2 + bias[2], go = a3 + bias[3];
        c = sigf(gf) * c + sigf(gi) * tanh_fast(gg);
        const float h = sigf(go) * tanh_fast(c);

        if (s == 0) vbuf[cur ^ 1][En + j2] = h;

        // out = h @ W2 + b2 (s==0 copies only contribute)
        float p0 = (s == 0) ? h * w2a : 0.0f;
        float p1 = (s == 0) ? h * w2b : 0.0f;
        #pragma unroll
        for (int off = 32; off; off >>= 1) {
            p0 += __shfl_xor(p0, off);
            p1 += __shfl_xor(p1, off);
        }
        if (lane == 0) { red[wv][0] = p0; red[wv][1] = p1; }
        __syncthreads();

        if (tid < 2) {
            float o = b2[tid];
            #pragma unroll
            for (int k2 = 0; k2 < 8; k2++) o += red[k2][tid];
            out[((size_t)b * Rn + r) * Fn + tid] = o;
            xin_sh[tid] = o;
        }
        __syncthreads();

        if (r + 1 < Rn && tid < En) {
            vbuf[cur ^ 1][tid] = fmaxf(xin_sh[0] * w1a + xin_sh[1] * w1b + b1v, 0.0f);
        }
        __syncthreads();
    }
}

extern "C" void kernel_launch(void* const* d_in, const int* in_sizes, int n_in,
                              void* d_out, int out_size, void* d_ws, size_t ws_size,
                              hipStream_t stream)
{
    const float* src    = (const float*)d_in[0];
    const float* W_res  = (const float*)d_in[2];
    const float* W_gcn  = (const float*)d_in[3];
    const float* b_gcn  = (const float*)d_in[4];
    const float* W_ih_e = (const float*)d_in[5];
    const float* W_hh_e = (const float*)d_in[6];
    const float* b_e    = (const float*)d_in[7];
    const float* W1     = (const float*)d_in[8];
    const float* b1     = (const float*)d_in[9];
    const float* W_ih_d = (const float*)d_in[10];
    const float* W_hh_d = (const float*)d_in[11];
    const float* b_d    = (const float*)d_in[12];
    const float* W2     = (const float*)d_in[13];
    const float* b2     = (const float*)d_in[14];

    float* out = (float*)d_out;
    float* emb = (float*)d_ws;   // Bn*Tn*En floats = 3.28 MB scratch

    k_emb<<<(Bn * Tn) / 4, 256, 0, stream>>>(src, W_res, W_gcn, b_gcn, emb);
    k_seq<<<Bn, 512, 0, stream>>>(emb, src,
                                  W_ih_e, W_hh_e, b_e,
                                  W1, b1,
                                  W_ih_d, W_hh_d, b_d,
                                  W2, b2, out);
}